// Round 23
// baseline (222.342 us; speedup 1.0000x reference)
//
#include <hip/hip_runtime.h>
#include <hip/hip_bf16.h>
#include <stdint.h>

#define M_DIM 8192   // 4*2048
#define N_DIM 4096   // OUT_FEATURES
#define K_DIM 4096   // IN_FEATURES

typedef __attribute__((ext_vector_type(4))) float f32x4;
typedef __attribute__((ext_vector_type(4))) int   i32x4;

#define GLD_LDS16(gaddr, laddr)                                            \
  __builtin_amdgcn_global_load_lds(                                        \
      (const __attribute__((address_space(1))) uint32_t*)(gaddr),          \
      (__attribute__((address_space(3))) uint32_t*)(laddr), 16, 0, 0)

// ---------------------------------------------------------------------------
// i8 subtile-major layout (BK=64), unchanged from R16:
//  t = k>>6 (64 K-tiles); rp = row>>8; h = (row>>7)&1; f = (row>>4)&7;
//  lane slot l = (row&15) + ((k>>4)&3)*16 ; byte-in-slot = k&15
//  byte = (rp*64 + t)*16384 + h*8192 + f*1024 + l*16 + (k&15)
// ---------------------------------------------------------------------------

// Merged prep (UNCHANGED from R16): [0,2048): W dequant->i8; [2048,10240): x.
__global__ __launch_bounds__(256) void prep_kernel(
    const int* __restrict__ q, const float* __restrict__ lut,
    signed char* __restrict__ Wq, float* __restrict__ sw,
    const float* __restrict__ x, signed char* __restrict__ Xq,
    float* __restrict__ sxd) {
  __shared__ char sm[16384];
  const int b = blockIdx.x;
  const int tid = threadIdx.x;
  if (b < 2048) {
    const int ob = b >> 4, wb = b & 15;
    const int o_l = tid >> 3, w_l = tid & 7;
    const int o = ob * 32 + o_l;
    const int PLANE = N_DIM * (K_DIM / 32);
    const int base = o * (K_DIM / 32) + wb * 8 + w_l;
    uint32_t q0 = (uint32_t)q[base];
    uint32_t q1 = (uint32_t)q[PLANE + base];
    uint32_t q2 = (uint32_t)q[2 * PLANE + base];
    uint32_t q3 = (uint32_t)q[3 * PLANE + base];
    const float* lrow = lut + o * 16;
    float lmax = 1e-30f;
#pragma unroll
    for (int j = 0; j < 16; ++j) lmax = fmaxf(lmax, fabsf(lrow[j]));
    const float qs = 127.0f / lmax;
    signed char l8[16];
#pragma unroll
    for (int j = 0; j < 16; ++j)
      l8[j] = (signed char)(int)rintf(lrow[j] * qs);
    if (wb == 0 && w_l == 0) sw[o] = lmax * (1.0f / 127.0f);

    union { i32x4 v; signed char c[16]; } u0, u1;
#pragma unroll
    for (int i = 0; i < 16; ++i) {
      uint32_t idx = ((q0 >> i) & 1u) | (((q1 >> i) & 1u) << 1) |
                     (((q2 >> i) & 1u) << 2) | (((q3 >> i) & 1u) << 3);
      u0.c[i] = l8[idx];
    }
#pragma unroll
    for (int i = 16; i < 32; ++i) {
      uint32_t idx = ((q0 >> i) & 1u) | (((q1 >> i) & 1u) << 1) |
                     (((q2 >> i) & 1u) << 2) | (((q3 >> i) & 1u) << 3);
      u1.c[i - 16] = l8[idx];
    }
    const int t_local = w_l >> 1;            // 0..3
    const int f_local = o_l >> 4;            // 0..1
    const int kc0 = (w_l & 1) * 2;           // 0 or 2
    char* sp = sm + t_local * 2048 + f_local * 1024;
    *(i32x4*)(sp + ((o_l & 15) + kc0 * 16) * 16)       = u0.v;
    *(i32x4*)(sp + ((o_l & 15) + (kc0 + 1) * 16) * 16) = u1.v;
    __syncthreads();
    const int rp = ob >> 3, h = (ob >> 2) & 1, f0 = (ob * 2) & 7;
#pragma unroll
    for (int c = 0; c < 2; ++c) {
      const int ci = c * 256 + tid;          // 0..511 slots of 16B
      const int t_loc = ci >> 7, off = ci & 127;
      const size_t outb = (size_t)(rp * 64 + wb * 4 + t_loc) * 16384
                          + h * 8192 + f0 * 1024 + off * 16;
      *(i32x4*)(Wq + outb) = *(i32x4*)(sm + t_loc * 2048 + off * 16);
    }
  } else {
    const int r = b - 2048;
    const float* xr = x + (size_t)r * K_DIM;
    float v[16];
#pragma unroll
    for (int s = 0; s < 4; ++s) {
      f32x4 u = *(const f32x4*)(xr + tid * 4 + s * 1024);
      v[s * 4 + 0] = u[0]; v[s * 4 + 1] = u[1];
      v[s * 4 + 2] = u[2]; v[s * 4 + 3] = u[3];
    }
    float m = 0.0f;
#pragma unroll
    for (int i = 0; i < 16; ++i) m = fmaxf(m, fabsf(v[i]));
#pragma unroll
    for (int off = 32; off; off >>= 1) m = fmaxf(m, __shfl_down(m, off));
    float* red = (float*)(sm + 8192);
    if ((tid & 63) == 0) red[tid >> 6] = m;
    __syncthreads();
    float rmax = fmaxf(fmaxf(red[0], red[1]), fmaxf(red[2], red[3]));
    rmax = fmaxf(rmax, 1e-30f);
    if (tid == 0) sxd[r] = rmax * (1.0f / 127.0f);
    const float qs = 127.0f / rmax;
#pragma unroll
    for (int s = 0; s < 4; ++s) {
      int qi[4];
#pragma unroll
      for (int j = 0; j < 4; ++j) {
        float qc = fminf(127.0f, fmaxf(-127.0f, rintf(v[s * 4 + j] * qs)));
        qi[j] = (int)qc;
      }
      uint32_t w = (qi[0] & 255) | ((qi[1] & 255) << 8) |
                   ((qi[2] & 255) << 16) | ((uint32_t)(qi[3] & 255) << 24);
      *(uint32_t*)(sm + tid * 4 + s * 1024) = w;
    }
    __syncthreads();
    const int rp = r >> 8, h = (r >> 7) & 1, f = (r >> 4) & 7;
    const int kt = tid >> 2, kc = tid & 3;
    const size_t outb = (size_t)(rp * 64 + kt) * 16384 + h * 8192
                        + f * 1024 + ((r & 15) + kc * 16) * 16;
    *(i32x4*)(Xq + outb) = *(i32x4*)(sm + tid * 16);
  }
}

// ---------------------------------------------------------------------------
// 256x128 i8 GEMM, R23: 2 BLOCKS/CU via small registers + small LDS.
// 8 waves (4M x 2N), per-wave 64x64 (acc 64 regs, operands 32 -> ~110 total,
// 4 waves/SIMD). Block-cooperative staging (24KB/tile = 3 gld_lds/thread,
// FETCH stays low). Ring-of-3 LDS = 72KB -> 2 blocks/CU (144KB <= 160).
// Phase t: {STAGE(t+2) [3 glds]; 8 linear b128 reads; 16 MFMA; lgkm0;
// VMC(3) certifies t+1 (staged >=1 phase ~1400cyc ago > 900 HBM); BAR}.
// WAR: stage(t+2) overwrites buf (t+2)%3, last read in phase t-1, drained
// by lgkm0+BAR at end of t-1. Inter-block drift supplies the overlap that
// single-block rounds (R16-R22, all ~150us) structurally lacked.
// ---------------------------------------------------------------------------
__global__ __launch_bounds__(512) void anyprec_gemm_kernel(
    const signed char* __restrict__ A,   // Xq subtile-major (32 panels)
    const signed char* __restrict__ B,   // Wq subtile-major (16 panels)
    const float* __restrict__ sxd, const float* __restrict__ sw,
    const float* __restrict__ bias,
    float* __restrict__ C) {
  __shared__ char lds[3][24576];   // ring: A 16KB at +0, B 8KB at +16384

  // XCD swizzle: nwg = 1024 (divisible by 8)
  int bid = blockIdx.x;
  int swz = (bid & 7) * 128 + (bid >> 3);
  int mb = swz >> 5;    // 32 m-tiles (256 rows)
  int nb = swz & 31;    // 32 n-tiles (128 cols)

  const int tid  = threadIdx.x;
  const int lane = tid & 63;
  const int wid  = tid >> 6;
  const int wm   = wid >> 1;   // 0..3 (64-row group)
  const int wn   = wid & 1;    // 0..1 (64-col group)
  const int tid16  = tid * 16;
  const int lane16 = lane * 16;

  char* lbase = &lds[0][0];

  // A tile t: 16KB at (mb*64 + t)*16384. B tile t: 8KB at
  // ((nb>>1)*64 + t)*16384 + (nb&1)*8192.
  const char* gA = (const char*)A + (size_t)mb * 1048576;
  const char* gB = (const char*)B + (size_t)(nb >> 1) * 1048576
                   + (nb & 1) * 8192;

  i32x4 acc[4][4];
#pragma unroll
  for (int mf = 0; mf < 4; ++mf)
#pragma unroll
    for (int nf = 0; nf < 4; ++nf) acc[mf][nf] = (i32x4)0;

  i32x4 a[4], b[4];

#define STAGE_T(t, rb) {                                                   \
    char* lb_ = lbase + (rb) * 24576 + tid16;                              \
    const char* ga_ = gA + (size_t)(t) * 16384 + tid16;                    \
    const char* gb_ = gB + (size_t)(t) * 16384 + tid16;                    \
    GLD_LDS16(ga_,        lb_);                                            \
    GLD_LDS16(ga_ + 8192, lb_ + 8192);                                     \
    GLD_LDS16(gb_,        lb_ + 16384); }

// A frags: row = wm*64 + mf*16 -> byte off = wm*4096 + mf*1024 (+lane*16)
#define LDAB(rb) {                                                         \
    const char* pa_ = lbase + (rb) * 24576 + wm * 4096 + lane16;           \
    const char* pb_ = lbase + (rb) * 24576 + 16384 + wn * 4096 + lane16;   \
    _Pragma("unroll")                                                      \
    for (int mf = 0; mf < 4; ++mf) a[mf] = *(const i32x4*)(pa_ + mf*1024); \
    _Pragma("unroll")                                                      \
    for (int nf = 0; nf < 4; ++nf) b[nf] = *(const i32x4*)(pb_ + nf*1024); }

#define MMA16 {                                                            \
    _Pragma("unroll")                                                      \
    for (int mf = 0; mf < 4; ++mf)                                         \
      _Pragma("unroll")                                                    \
      for (int nf = 0; nf < 4; ++nf)                                       \
        acc[mf][nf] = __builtin_amdgcn_mfma_i32_16x16x64_i8(               \
            a[mf], b[nf], acc[mf][nf], 0, 0, 0); }

#define PRIO1 __builtin_amdgcn_s_setprio(1);
#define PRIO0 __builtin_amdgcn_s_setprio(0);
#define BAR   __builtin_amdgcn_s_barrier();
#define LGKM0 asm volatile("s_waitcnt lgkmcnt(0)" ::: "memory");
#define VMC(n) asm volatile("s_waitcnt vmcnt(" #n ")" ::: "memory");

  // ---- prologue: stage tiles 0,1; certify tile 0 (leave tile1's 3 loads)
  STAGE_T(0, 0);
  STAGE_T(1, 1);
  VMC(3); BAR;

  // ---- main loop: t = 0..61 (stage t+2 <= 63)
  for (int t = 0; t < 62; ++t) {
    const int rb = t % 3;
    STAGE_T(t + 2, (t + 2) % 3);
    LDAB(rb);
    PRIO1; MMA16; PRIO0;
    LGKM0;                          // my reads drained (WAR collective at BAR)
    VMC(3);                         // certify tile t+1 (staged >=1 phase ago)
    BAR;
  }
  // ---- t = 62: no stage; certify tile 63 fully
  {
    LDAB(62 % 3);
    PRIO1; MMA16; PRIO0;
    LGKM0; VMC(0); BAR;
  }
  // ---- t = 63
  {
    LDAB(63 % 3);
    PRIO1; MMA16; PRIO0;
  }

  // ---- epilogue: C/D layout col=lane&15, row=(lane>>4)*4+j (dtype-indep)
  const int cL = lane & 15;
  const int rL = (lane >> 4) * 4;
#pragma unroll
  for (int nf = 0; nf < 4; ++nf) {
    int col = nb * 128 + wn * 64 + nf * 16 + cL;
    float bv  = bias[col];
    float swc = sw[col];
#pragma unroll
    for (int mf = 0; mf < 4; ++mf) {
      int row0 = mb * 256 + wm * 64 + mf * 16 + rL;
#pragma unroll
      for (int j = 0; j < 4; ++j) {
        int row = row0 + j;
        float s = sxd[row] * swc;
        C[(size_t)row * N_DIM + col] =
            fmaf((float)acc[mf][nf][j], s, bv);
      }
    }
  }
#undef STAGE_T
#undef LDAB
#undef MMA16
#undef PRIO1
#undef PRIO0
#undef BAR
#undef LGKM0
#undef VMC
}

extern "C" void kernel_launch(void* const* d_in, const int* in_sizes, int n_in,
                              void* d_out, int out_size, void* d_ws, size_t ws_size,
                              hipStream_t stream) {
  const float* x    = (const float*)d_in[0];
  const int*   qw   = (const int*)d_in[1];
  const float* lut  = (const float*)d_in[2];
  const float* bias = (const float*)d_in[3];

  char* wsb = (char*)d_ws;
  signed char* Wq  = (signed char*)wsb;                         // 16 MB
  signed char* Xq  = (signed char*)(wsb + (size_t)16 * 1024 * 1024);  // 32 MB
  float*       sxd = (float*)(wsb + (size_t)48 * 1024 * 1024);  // 32 KB
  float*       sw  = sxd + M_DIM;                               // 16 KB

  {
    prep_kernel<<<10240, 256, 0, stream>>>(qw, lut, Wq, sw, x, Xq, sxd);
  }
  {
    dim3 grid((M_DIM / 256) * (N_DIM / 128));  // 32*32 = 1024, 2 blocks/CU
    anyprec_gemm_kernel<<<grid, 512, 0, stream>>>(Xq, Wq, sxd, sw, bias,
                                                  (float*)d_out);
  }
}

// Round 25
// 191.489 us; speedup vs baseline: 1.1611x; 1.1611x over previous
//
#include <hip/hip_runtime.h>
#include <hip/hip_bf16.h>
#include <stdint.h>

#define M_DIM 8192   // 4*2048
#define N_DIM 4096   // OUT_FEATURES
#define K_DIM 4096   // IN_FEATURES

typedef __attribute__((ext_vector_type(4))) float f32x4;
typedef __attribute__((ext_vector_type(4))) int   i32x4;

#define GLD_LDS16(gaddr, laddr)                                            \
  __builtin_amdgcn_global_load_lds(                                        \
      (const __attribute__((address_space(1))) uint32_t*)(gaddr),          \
      (__attribute__((address_space(3))) uint32_t*)(laddr), 16, 0, 0)

// ---------------------------------------------------------------------------
// i8 subtile-major layout (BK=64), unchanged from R16:
//  t = k>>6 (64 K-tiles); rp = row>>8; h = (row>>7)&1; f = (row>>4)&7;
//  lane slot l = (row&15) + ((k>>4)&3)*16 ; byte-in-slot = k&15
//  byte = (rp*64 + t)*16384 + h*8192 + f*1024 + l*16 + (k&15)
// ---------------------------------------------------------------------------

// Merged prep (UNCHANGED from R16): [0,2048): W dequant->i8; [2048,10240): x.
__global__ __launch_bounds__(256) void prep_kernel(
    const int* __restrict__ q, const float* __restrict__ lut,
    signed char* __restrict__ Wq, float* __restrict__ sw,
    const float* __restrict__ x, signed char* __restrict__ Xq,
    float* __restrict__ sxd) {
  __shared__ char sm[16384];
  const int b = blockIdx.x;
  const int tid = threadIdx.x;
  if (b < 2048) {
    const int ob = b >> 4, wb = b & 15;
    const int o_l = tid >> 3, w_l = tid & 7;
    const int o = ob * 32 + o_l;
    const int PLANE = N_DIM * (K_DIM / 32);
    const int base = o * (K_DIM / 32) + wb * 8 + w_l;
    uint32_t q0 = (uint32_t)q[base];
    uint32_t q1 = (uint32_t)q[PLANE + base];
    uint32_t q2 = (uint32_t)q[2 * PLANE + base];
    uint32_t q3 = (uint32_t)q[3 * PLANE + base];
    const float* lrow = lut + o * 16;
    float lmax = 1e-30f;
#pragma unroll
    for (int j = 0; j < 16; ++j) lmax = fmaxf(lmax, fabsf(lrow[j]));
    const float qs = 127.0f / lmax;
    signed char l8[16];
#pragma unroll
    for (int j = 0; j < 16; ++j)
      l8[j] = (signed char)(int)rintf(lrow[j] * qs);
    if (wb == 0 && w_l == 0) sw[o] = lmax * (1.0f / 127.0f);

    union { i32x4 v; signed char c[16]; } u0, u1;
#pragma unroll
    for (int i = 0; i < 16; ++i) {
      uint32_t idx = ((q0 >> i) & 1u) | (((q1 >> i) & 1u) << 1) |
                     (((q2 >> i) & 1u) << 2) | (((q3 >> i) & 1u) << 3);
      u0.c[i] = l8[idx];
    }
#pragma unroll
    for (int i = 16; i < 32; ++i) {
      uint32_t idx = ((q0 >> i) & 1u) | (((q1 >> i) & 1u) << 1) |
                     (((q2 >> i) & 1u) << 2) | (((q3 >> i) & 1u) << 3);
      u1.c[i - 16] = l8[idx];
    }
    const int t_local = w_l >> 1;            // 0..3
    const int f_local = o_l >> 4;            // 0..1
    const int kc0 = (w_l & 1) * 2;           // 0 or 2
    char* sp = sm + t_local * 2048 + f_local * 1024;
    *(i32x4*)(sp + ((o_l & 15) + kc0 * 16) * 16)       = u0.v;
    *(i32x4*)(sp + ((o_l & 15) + (kc0 + 1) * 16) * 16) = u1.v;
    __syncthreads();
    const int rp = ob >> 3, h = (ob >> 2) & 1, f0 = (ob * 2) & 7;
#pragma unroll
    for (int c = 0; c < 2; ++c) {
      const int ci = c * 256 + tid;          // 0..511 slots of 16B
      const int t_loc = ci >> 7, off = ci & 127;
      const size_t outb = (size_t)(rp * 64 + wb * 4 + t_loc) * 16384
                          + h * 8192 + f0 * 1024 + off * 16;
      *(i32x4*)(Wq + outb) = *(i32x4*)(sm + t_loc * 2048 + off * 16);
    }
  } else {
    const int r = b - 2048;
    const float* xr = x + (size_t)r * K_DIM;
    float v[16];
#pragma unroll
    for (int s = 0; s < 4; ++s) {
      f32x4 u = *(const f32x4*)(xr + tid * 4 + s * 1024);
      v[s * 4 + 0] = u[0]; v[s * 4 + 1] = u[1];
      v[s * 4 + 2] = u[2]; v[s * 4 + 3] = u[3];
    }
    float m = 0.0f;
#pragma unroll
    for (int i = 0; i < 16; ++i) m = fmaxf(m, fabsf(v[i]));
#pragma unroll
    for (int off = 32; off; off >>= 1) m = fmaxf(m, __shfl_down(m, off));
    float* red = (float*)(sm + 8192);
    if ((tid & 63) == 0) red[tid >> 6] = m;
    __syncthreads();
    float rmax = fmaxf(fmaxf(red[0], red[1]), fmaxf(red[2], red[3]));
    rmax = fmaxf(rmax, 1e-30f);
    if (tid == 0) sxd[r] = rmax * (1.0f / 127.0f);
    const float qs = 127.0f / rmax;
#pragma unroll
    for (int s = 0; s < 4; ++s) {
      int qi[4];
#pragma unroll
      for (int j = 0; j < 4; ++j) {
        float qc = fminf(127.0f, fmaxf(-127.0f, rintf(v[s * 4 + j] * qs)));
        qi[j] = (int)qc;
      }
      uint32_t w = (qi[0] & 255) | ((qi[1] & 255) << 8) |
                   ((qi[2] & 255) << 16) | ((uint32_t)(qi[3] & 255) << 24);
      *(uint32_t*)(sm + tid * 4 + s * 1024) = w;
    }
    __syncthreads();
    const int rp = r >> 8, h = (r >> 7) & 1, f = (r >> 4) & 7;
    const int kt = tid >> 2, kc = tid & 3;
    const size_t outb = (size_t)(rp * 64 + kt) * 16384 + h * 8192
                        + f * 1024 + ((r & 15) + kc * 16) * 16;
    *(i32x4*)(Xq + outb) = *(i32x4*)(sm + tid * 16);
  }
}

// ---------------------------------------------------------------------------
// 256x256 i8 GEMM, R25 = R24 (anti-convoy wave-group stagger) with the macro
// arity fixed. Even waves: quadrants (0,.) first; odd waves: mirror (1,.)
// first. Sync skeleton identical to R22 (1 barrier + VMC(4) cert per tile;
// matched barrier counts both branches; phase-level WAR order-independent).
// ---------------------------------------------------------------------------
__global__ __launch_bounds__(512, 2) void anyprec_gemm_kernel(
    const signed char* __restrict__ A,   // Xq subtile-major
    const signed char* __restrict__ B,   // Wq subtile-major
    const float* __restrict__ sxd, const float* __restrict__ sw,
    const float* __restrict__ bias,
    float* __restrict__ C) {
  __shared__ char lds[4][32768];   // ring: A tile 16KB at +0, B at +16384

  int bid = blockIdx.x;
  int swz = (bid & 7) * 64 + (bid >> 3);
  int mb = swz >> 4;    // 32 m-tiles
  int nb = swz & 15;    // 16 n-tiles

  const int tid  = threadIdx.x;
  const int lane = tid & 63;
  const int wid  = tid >> 6;
  const int wr   = wid >> 2;   // 0..1
  const int wc   = wid & 3;    // 0..3
  const int tid16  = tid * 16;
  const int lane16 = lane * 16;

  char* lbase = &lds[0][0];

  const char* gA = (const char*)A + (size_t)mb * 1048576;  // 64 tiles * 16KB
  const char* gB = (const char*)B + (size_t)nb * 1048576;

  i32x4 acc[2][2][4][2];
#pragma unroll
  for (int qm = 0; qm < 2; ++qm)
#pragma unroll
    for (int qn = 0; qn < 2; ++qn)
#pragma unroll
      for (int mf = 0; mf < 4; ++mf)
#pragma unroll
        for (int nf = 0; nf < 2; ++nf) acc[qm][qn][mf][nf] = (i32x4)0;

  i32x4 a0[4], a1[4], b0[2], b1[2];

#define STAGE_T(t, rb) {                                                   \
    char* lb_ = lbase + (rb) * 32768 + tid16;                              \
    const char* ga_ = gA + (size_t)(t) * 16384 + tid16;                    \
    const char* gb_ = gB + (size_t)(t) * 16384 + tid16;                    \
    GLD_LDS16(ga_,        lb_);                                            \
    GLD_LDS16(ga_ + 8192, lb_ + 8192);                                     \
    GLD_LDS16(gb_,        lb_ + 16384);                                    \
    GLD_LDS16(gb_ + 8192, lb_ + 24576); }

// A: row = qm*128 + wr*64 + mf*16 -> h=qm, f=wr*4+mf; A at buf+0
#define LDA(dst, qm, rb) {                                                 \
    const char* p_ = lbase + (rb) * 32768 + (qm) * 8192 + wr * 4096        \
                     + lane16;                                             \
    _Pragma("unroll")                                                      \
    for (int mf = 0; mf < 4; ++mf)                                         \
      dst[mf] = *(const i32x4*)(p_ + mf * 1024); }

// B: col = qn*128 + wc*32 + nf*16 -> h=qn, f=wc*2+nf; B at buf+16384
#define LDB(dst, qn, rb) {                                                 \
    const char* p_ = lbase + (rb) * 32768 + 16384 + (qn) * 8192            \
                     + wc * 2048 + lane16;                                 \
    _Pragma("unroll")                                                      \
    for (int nf = 0; nf < 2; ++nf)                                         \
      dst[nf] = *(const i32x4*)(p_ + nf * 1024); }

#define MMA(qm, qn, aa, bb) {                                              \
    _Pragma("unroll")                                                      \
    for (int mf = 0; mf < 4; ++mf)                                         \
      _Pragma("unroll")                                                    \
      for (int nf = 0; nf < 2; ++nf)                                       \
        acc[qm][qn][mf][nf] = __builtin_amdgcn_mfma_i32_16x16x64_i8(       \
            aa[mf], bb[nf], acc[qm][qn][mf][nf], 0, 0, 0); }

#define PRIO1 __builtin_amdgcn_s_setprio(1);
#define PRIO0 __builtin_amdgcn_s_setprio(0);
#define BAR   __builtin_amdgcn_s_barrier();
#define VMC(n) asm volatile("s_waitcnt vmcnt(" #n ")" ::: "memory");

// Even-wave phase body: quadrants (0,.) first; read a1(t); prefetch t+1
#define BODY_A(rb, rn)                                                     \
    PRIO1;                                                                 \
    LDA(a1, 1, rb);                                                        \
    MMA(0, 0, a0, b0); MMA(0, 1, a0, b1);                                  \
    LDA(a0, 0, rn);                                                        \
    MMA(1, 1, a1, b1); LDB(b1, 1, rn);                                     \
    MMA(1, 0, a1, b0); LDB(b0, 0, rn);                                     \
    PRIO0;

// Odd-wave phase body (mirror): quadrants (1,.) first; read a0(t)
#define BODY_B(rb, rn)                                                     \
    PRIO1;                                                                 \
    LDA(a0, 0, rb);                                                        \
    MMA(1, 1, a1, b1); MMA(1, 0, a1, b0);                                  \
    LDA(a1, 1, rn);                                                        \
    MMA(0, 0, a0, b0); LDB(b0, 0, rn);                                     \
    MMA(0, 1, a0, b1); LDB(b1, 1, rn);                                     \
    PRIO0;

  // ---- prologue: stage tiles 0,1,2; certify tiles 0 AND 1 (VMC(4))
  STAGE_T(0, 0);
  STAGE_T(1, 1);
  STAGE_T(2, 2);
  VMC(4); BAR;

  if ((wid & 1) == 0) {
    // ================= even waves =================
    LDA(a0, 0, 0); LDB(b0, 0, 0); LDB(b1, 1, 0);
    for (int t = 0; t < 61; ++t) {
      const int rb = t & 3, rn = (t + 1) & 3;
      STAGE_T(t + 3, (t + 3) & 3);
      BODY_A(rb, rn);
      VMC(4); BAR;
    }
    // t = 61: certify 63 fully
    BODY_A(1, 2);
    VMC(0); BAR;
    // t = 62 (no stage/barrier)
    BODY_A(2, 3);
    // t = 63
    PRIO1;
    LDA(a1, 1, 3);
    MMA(0, 0, a0, b0); MMA(0, 1, a0, b1);
    MMA(1, 1, a1, b1); MMA(1, 0, a1, b0);
    PRIO0;
  } else {
    // ================= odd waves (mirror) =================
    LDA(a1, 1, 0); LDB(b1, 1, 0); LDB(b0, 0, 0);
    for (int t = 0; t < 61; ++t) {
      const int rb = t & 3, rn = (t + 1) & 3;
      STAGE_T(t + 3, (t + 3) & 3);
      BODY_B(rb, rn);
      VMC(4); BAR;
    }
    // t = 61: certify 63 fully
    BODY_B(1, 2);
    VMC(0); BAR;
    // t = 62 (no stage/barrier)
    BODY_B(2, 3);
    // t = 63
    PRIO1;
    LDA(a0, 0, 3);
    MMA(1, 1, a1, b1); MMA(1, 0, a1, b0);
    MMA(0, 0, a0, b0); MMA(0, 1, a0, b1);
    PRIO0;
  }

  // ---- epilogue: C/D layout col=lane&15, row=(lane>>4)*4+j (dtype-indep)
  const int cL = lane & 15;
  const int rL = (lane >> 4) * 4;
#pragma unroll
  for (int qn = 0; qn < 2; ++qn)
#pragma unroll
    for (int nf = 0; nf < 2; ++nf) {
      int col = nb * 256 + qn * 128 + wc * 32 + nf * 16 + cL;
      float bv  = bias[col];
      float swc = sw[col];
#pragma unroll
      for (int qm = 0; qm < 2; ++qm)
#pragma unroll
        for (int mf = 0; mf < 4; ++mf) {
          int row0 = mb * 256 + qm * 128 + wr * 64 + mf * 16 + rL;
#pragma unroll
          for (int j = 0; j < 4; ++j) {
            int row = row0 + j;
            float s = sxd[row] * swc;
            C[(size_t)row * N_DIM + col] =
                fmaf((float)acc[qm][qn][mf][nf][j], s, bv);
          }
        }
    }
#undef STAGE_T
#undef LDA
#undef LDB
#undef MMA
#undef PRIO1
#undef PRIO0
#undef BAR
#undef VMC
#undef BODY_A
#undef BODY_B
}

extern "C" void kernel_launch(void* const* d_in, const int* in_sizes, int n_in,
                              void* d_out, int out_size, void* d_ws, size_t ws_size,
                              hipStream_t stream) {
  const float* x    = (const float*)d_in[0];
  const int*   qw   = (const int*)d_in[1];
  const float* lut  = (const float*)d_in[2];
  const float* bias = (const float*)d_in[3];

  char* wsb = (char*)d_ws;
  signed char* Wq  = (signed char*)wsb;                         // 16 MB
  signed char* Xq  = (signed char*)(wsb + (size_t)16 * 1024 * 1024);  // 32 MB
  float*       sxd = (float*)(wsb + (size_t)48 * 1024 * 1024);  // 32 KB
  float*       sw  = sxd + M_DIM;                               // 16 KB

  {
    prep_kernel<<<10240, 256, 0, stream>>>(qw, lut, Wq, sw, x, Xq, sxd);
  }
  {
    dim3 grid((M_DIM / 256) * (N_DIM / 256));  // 32*16 = 512
    anyprec_gemm_kernel<<<grid, 512, 0, stream>>>(Xq, Wq, sxd, sw, bias,
                                                  (float*)d_out);
  }
}